// Round 2
// baseline (464.911 us; speedup 1.0000x reference)
//
#include <hip/hip_runtime.h>
#include <cstdint>
#include <cmath>

#define L_ 4096
#define D_ 1024
#define H_ 16
#define HD_ 64
#define M_ 4096

typedef __bf16 bf16_t;
typedef __attribute__((ext_vector_type(8))) __bf16 bf16x8;
typedef __attribute__((ext_vector_type(4))) float f32x4;

__device__ __forceinline__ f32x4 mfma16(bf16x8 a, bf16x8 b, f32x4 c) {
    return __builtin_amdgcn_mfma_f32_16x16x32_bf16(a, b, c, 0, 0, 0);
}

// async global->LDS, 16B per lane. lds ptr must be wave-uniform base; HW adds lane*16.
__device__ __forceinline__ void gload_lds16(const bf16_t* g, bf16_t* l) {
    __builtin_amdgcn_global_load_lds(
        (const __attribute__((address_space(1))) unsigned int*)(g),
        (__attribute__((address_space(3))) unsigned int*)(l), 16, 0, 0);
}

// ---------------------------------------------------------------------------
// LayerNorm: fp32 (rows x 1024) -> bf16, y = (x-mu)*rsqrt(var+eps)*g + b
// ---------------------------------------------------------------------------
__global__ __launch_bounds__(256) void ln_kernel(const float* __restrict__ x,
                                                 const float* __restrict__ g,
                                                 const float* __restrict__ b,
                                                 bf16_t* __restrict__ out) {
    int row = blockIdx.x, tid = threadIdx.x;
    int wave = tid >> 6, lane = tid & 63;
    const float* xr = x + (long)row * D_;
    float v[4];
    float s = 0.f;
#pragma unroll
    for (int i = 0; i < 4; i++) { v[i] = xr[tid + 256 * i]; s += v[i]; }
    __shared__ float red[8];
#pragma unroll
    for (int off = 32; off > 0; off >>= 1) s += __shfl_down(s, off, 64);
    if (lane == 0) red[wave] = s;
    __syncthreads();
    float mean = (red[0] + red[1] + red[2] + red[3]) * (1.f / 1024.f);
    float s2 = 0.f;
#pragma unroll
    for (int i = 0; i < 4; i++) { float d = v[i] - mean; s2 += d * d; }
#pragma unroll
    for (int off = 32; off > 0; off >>= 1) s2 += __shfl_down(s2, off, 64);
    __syncthreads();
    if (lane == 0) red[wave] = s2;
    __syncthreads();
    float var = (red[0] + red[1] + red[2] + red[3]) * (1.f / 1024.f);
    float rstd = rsqrtf(var + 1e-5f);
#pragma unroll
    for (int i = 0; i < 4; i++) {
        int c = tid + 256 * i;
        out[(long)row * D_ + c] = (bf16_t)((v[i] - mean) * rstd * g[c] + b[c]);
    }
}

// ---------------------------------------------------------------------------
// Transpose + cast: W (K x N fp32, row-major) -> Wt (N x K bf16, row-major)
// ---------------------------------------------------------------------------
__global__ __launch_bounds__(256) void transpose_cast(const float* __restrict__ W,
                                                      bf16_t* __restrict__ Wt,
                                                      int K, int N) {
    __shared__ float t[32][33];
    int n0 = blockIdx.x * 32, k0 = blockIdx.y * 32;
    int tx = threadIdx.x & 31, ty = threadIdx.x >> 5;  // ty in 0..7
#pragma unroll
    for (int r = 0; r < 32; r += 8)
        t[ty + r][tx] = W[(long)(k0 + ty + r) * N + n0 + tx];
    __syncthreads();
#pragma unroll
    for (int r = 0; r < 32; r += 8)
        Wt[(long)(n0 + ty + r) * K + k0 + tx] = (bf16_t)t[tx][ty + r];
}

// ---------------------------------------------------------------------------
// RoPE in-place on qkv bf16 buffer (L x 3072). q cols [0,1024), k cols [1024,2048)
// freqs: (L, 32, 2) fp32
// ---------------------------------------------------------------------------
__global__ __launch_bounds__(256) void rope_kernel(bf16_t* __restrict__ qkv,
                                                   const float* __restrict__ freqs) {
    int idx = blockIdx.x * 256 + threadIdx.x;  // (l, h, d2): 4096*16*32
    int d2 = idx & 31;
    int h = (idx >> 5) & 15;
    int l = idx >> 9;
    float c = freqs[((long)l * 32 + d2) * 2 + 0];
    float s = freqs[((long)l * 32 + d2) * 2 + 1];
    bf16_t* q = qkv + (long)l * 3072 + h * 64 + 2 * d2;
    float a = (float)q[0], bb = (float)q[1];
    q[0] = (bf16_t)(a * c - bb * s);
    q[1] = (bf16_t)(a * s + bb * c);
    bf16_t* k = q + 1024;
    a = (float)k[0]; bb = (float)k[1];
    k[0] = (bf16_t)(a * c - bb * s);
    k[1] = (bf16_t)(a * s + bb * c);
}

// ---------------------------------------------------------------------------
// GEMM: C(MxN) = A(MxK bf16 rm) * Bt(NxK bf16 rm)^T, m97-style 128x128x32 tile.
// Epilogues: 0 = store bf16; 1 = +residual(full) -> fp32
//            2 = +bias(col), gelu -> bf16;  3 = +bias(col) + h(full) -> fp32
// ---------------------------------------------------------------------------
template <int EPI>
__global__ __launch_bounds__(256) void gemm_bt(const bf16_t* __restrict__ A,
                                               const bf16_t* __restrict__ Bt,
                                               int M, int N, int K,
                                               float* __restrict__ outF,
                                               bf16_t* __restrict__ outB,
                                               const float* __restrict__ extra1,
                                               const float* __restrict__ extra2) {
    __shared__ __align__(16) bf16_t As[128 * 32];
    __shared__ __align__(16) bf16_t Bs[128 * 32];
    int tid = threadIdx.x;
    int wave = tid >> 6, lane = tid & 63;
    int quad = lane >> 4, l16 = lane & 15;
    int wr = wave >> 1, wc = wave & 1;
    long bm = (long)blockIdx.y * 128, bn = (long)blockIdx.x * 128;

    f32x4 acc[4][4];
#pragma unroll
    for (int i = 0; i < 4; i++)
#pragma unroll
        for (int j = 0; j < 4; j++) acc[i][j] = (f32x4){0.f, 0.f, 0.f, 0.f};

    // staging: wave w stages rows [32w, 32w+32) of each tile, 2 insts x 16 rows
    const bf16_t* a_base = A + (bm + wave * 32 + (lane >> 2)) * (long)K + (lane & 3) * 8;
    const bf16_t* b_base = Bt + (bn + wave * 32 + (lane >> 2)) * (long)K + (lane & 3) * 8;
    bf16_t* as_dst0 = &As[(wave * 32 + 0) * 32];
    bf16_t* as_dst1 = &As[(wave * 32 + 16) * 32];
    bf16_t* bs_dst0 = &Bs[(wave * 32 + 0) * 32];
    bf16_t* bs_dst1 = &Bs[(wave * 32 + 16) * 32];

    for (int k0 = 0; k0 < K; k0 += 32) {
        __syncthreads();  // all waves done reading previous tiles
        gload_lds16(a_base + k0, as_dst0);
        gload_lds16(a_base + k0 + (long)16 * K, as_dst1);
        gload_lds16(b_base + k0, bs_dst0);
        gload_lds16(b_base + k0 + (long)16 * K, bs_dst1);
        __builtin_amdgcn_s_waitcnt(0);
        __syncthreads();

        bf16x8 af[4], bf[4];
#pragma unroll
        for (int i = 0; i < 4; i++) {
            af[i] = *(const bf16x8*)&As[(wr * 64 + i * 16 + l16) * 32 + quad * 8];
            bf[i] = *(const bf16x8*)&Bs[(wc * 64 + i * 16 + l16) * 32 + quad * 8];
        }
#pragma unroll
        for (int i = 0; i < 4; i++)
#pragma unroll
            for (int j = 0; j < 4; j++)
                acc[i][j] = mfma16(af[i], bf[j], acc[i][j]);
    }

    long base_row = bm + wr * 64;
    long base_col = bn + wc * 64;
#pragma unroll
    for (int i = 0; i < 4; i++)
#pragma unroll
        for (int j = 0; j < 4; j++)
#pragma unroll
            for (int r = 0; r < 4; r++) {
                long row = base_row + i * 16 + quad * 4 + r;
                long col = base_col + j * 16 + l16;
                long idx = row * (long)N + col;
                float v = acc[i][j][r];
                if (EPI == 0) {
                    outB[idx] = (bf16_t)v;
                } else if (EPI == 1) {
                    outF[idx] = v + extra1[idx];
                } else if (EPI == 2) {
                    v += extra1[col];
                    v = 0.5f * v * (1.0f + erff(v * 0.70710678118f));
                    outB[idx] = (bf16_t)v;
                } else {
                    outF[idx] = v + extra1[col] + extra2[idx];
                }
            }
}

// ---------------------------------------------------------------------------
// Flash attention over block-diagonal segments.
// grid: (qt=16, head=16, seg=4); block 256 = 4 waves; each block: 64 q-rows.
// qkv: L x 3072 bf16 (q|k|v each 1024 cols, col = h*64+hd). out: L x 1024 bf16.
// ---------------------------------------------------------------------------
__global__ __launch_bounds__(256) void attn_kernel(const bf16_t* __restrict__ qkv,
                                                   const int* __restrict__ cu,
                                                   bf16_t* __restrict__ out) {
    __shared__ __align__(16) bf16_t Qs[64 * 64];
    __shared__ __align__(16) bf16_t Ks[64 * 64];
    __shared__ __align__(16) bf16_t Vs[64 * 64];  // transposed: Vs[hd][key]
    __shared__ __align__(16) bf16_t Ps[4][16 * 64];

    int tid = threadIdx.x, wave = tid >> 6, lane = tid & 63;
    int quad = lane >> 4, l16 = lane & 15;
    int qt = blockIdx.x, head = blockIdx.y, seg = blockIdx.z;
    int s0 = cu[seg], s1 = cu[seg + 1];
    int r0 = s0 + qt * 64;
    const long hoff = (long)head * 64;

    // stage Q: wave w -> rows [16w, 16w+16), 2 insts x 8 rows (1KB each)
#pragma unroll
    for (int i = 0; i < 2; i++) {
        int row = wave * 16 + i * 8 + (lane >> 3);
        gload_lds16(qkv + (long)(r0 + row) * 3072 + hoff + (lane & 7) * 8,
                    &Qs[(wave * 16 + i * 8) * 64]);
    }

    f32x4 o[4];
#pragma unroll
    for (int j = 0; j < 4; j++) o[j] = (f32x4){0.f, 0.f, 0.f, 0.f};
    float mrow[4], lrow[4];
#pragma unroll
    for (int r = 0; r < 4; r++) { mrow[r] = -1e30f; lrow[r] = 0.f; }

    const float scale = 0.125f;  // 1/sqrt(64)

    for (int kt = s0; kt < s1; kt += 64) {
        __syncthreads();  // prev K/V consumers done
#pragma unroll
        for (int i = 0; i < 2; i++) {
            int row = wave * 16 + i * 8 + (lane >> 3);
            gload_lds16(qkv + (long)(kt + row) * 3072 + 1024 + hoff + (lane & 7) * 8,
                        &Ks[(wave * 16 + i * 8) * 64]);
        }
        {  // V transposed into LDS
            int key = tid >> 2;
            int hd0 = (tid & 3) * 16;
            const bf16_t* vsrc = qkv + (long)(kt + key) * 3072 + 2048 + hoff + hd0;
#pragma unroll
            for (int e = 0; e < 16; e++) Vs[(hd0 + e) * 64 + key] = vsrc[e];
        }
        __builtin_amdgcn_s_waitcnt(0);
        __syncthreads();

        // S strip (16 q-rows x 64 keys) for this wave
        f32x4 sacc[4];
#pragma unroll
        for (int j = 0; j < 4; j++) sacc[j] = (f32x4){0.f, 0.f, 0.f, 0.f};
#pragma unroll
        for (int j = 0; j < 4; j++)
#pragma unroll
            for (int ks = 0; ks < 2; ks++) {
                bf16x8 a = *(const bf16x8*)&Qs[(wave * 16 + l16) * 64 + ks * 32 + quad * 8];
                bf16x8 b = *(const bf16x8*)&Ks[(j * 16 + l16) * 64 + ks * 32 + quad * 8];
                sacc[j] = mfma16(a, b, sacc[j]);
            }

        // online softmax update
        float alpha[4];
#pragma unroll
        for (int r = 0; r < 4; r++) {
            float mx = sacc[0][r];
            mx = fmaxf(mx, sacc[1][r]);
            mx = fmaxf(mx, sacc[2][r]);
            mx = fmaxf(mx, sacc[3][r]);
            mx *= scale;
#pragma unroll
            for (int off = 1; off < 16; off <<= 1) mx = fmaxf(mx, __shfl_xor(mx, off, 64));
            float mnew = fmaxf(mrow[r], mx);
            alpha[r] = expf(mrow[r] - mnew);
            mrow[r] = mnew;
        }
        float rs[4] = {0.f, 0.f, 0.f, 0.f};
#pragma unroll
        for (int j = 0; j < 4; j++)
#pragma unroll
            for (int r = 0; r < 4; r++) {
                float p = expf(sacc[j][r] * scale - mrow[r]);
                rs[r] += p;
                Ps[wave][(quad * 4 + r) * 64 + j * 16 + l16] = (bf16_t)p;
            }
#pragma unroll
        for (int r = 0; r < 4; r++) {
#pragma unroll
            for (int off = 1; off < 16; off <<= 1) rs[r] += __shfl_xor(rs[r], off, 64);
            lrow[r] = lrow[r] * alpha[r] + rs[r];
        }
#pragma unroll
        for (int j = 0; j < 4; j++)
#pragma unroll
            for (int r = 0; r < 4; r++) o[j][r] *= alpha[r];

        __builtin_amdgcn_s_waitcnt(0);  // Ps writes visible to own wave's ds_read

        // O += P @ V  (P: 16 x 64 in A-layout from LDS; V^T rows are n)
#pragma unroll
        for (int j2 = 0; j2 < 4; j2++)
#pragma unroll
            for (int ks = 0; ks < 2; ks++) {
                bf16x8 a = *(const bf16x8*)&Ps[wave][l16 * 64 + ks * 32 + quad * 8];
                bf16x8 b = *(const bf16x8*)&Vs[(j2 * 16 + l16) * 64 + ks * 32 + quad * 8];
                o[j2] = mfma16(a, b, o[j2]);
            }
    }

#pragma unroll
    for (int j2 = 0; j2 < 4; j2++)
#pragma unroll
        for (int r = 0; r < 4; r++) {
            int row = r0 + wave * 16 + quad * 4 + r;
            out[(long)row * 1024 + head * 64 + j2 * 16 + l16] = (bf16_t)(o[j2][r] / lrow[r]);
        }
}

// ---------------------------------------------------------------------------
extern "C" void kernel_launch(void* const* d_in, const int* in_sizes, int n_in,
                              void* d_out, int out_size, void* d_ws, size_t ws_size,
                              hipStream_t stream) {
    const float* hidden = (const float*)d_in[0];
    const int* cu = (const int*)d_in[1];
    const float* freqs = (const float*)d_in[2];
    const float* ln0_g = (const float*)d_in[3];
    const float* ln0_b = (const float*)d_in[4];
    const float* ln1_g = (const float*)d_in[5];
    const float* ln1_b = (const float*)d_in[6];
    const float* w_qkv = (const float*)d_in[7];
    const float* w_o = (const float*)d_in[8];
    const float* w_fc0 = (const float*)d_in[9];
    const float* b_fc0 = (const float*)d_in[10];
    const float* w_fc1 = (const float*)d_in[11];
    const float* b_fc1 = (const float*)d_in[12];
    float* out = (float*)d_out;

    // workspace layout (bytes). act overlaps qkv+attn (dead by FC0 time).
    char* ws = (char*)d_ws;
    bf16_t* qkv = (bf16_t*)(ws);                             // 24 MB  [0,24M)
    bf16_t* attn = (bf16_t*)(ws + ((size_t)24 << 20));       //  8 MB  [24M,32M)
    bf16_t* act = (bf16_t*)(ws);                             // 32 MB  [0,32M) after attn dead
    bf16_t* x_bf = (bf16_t*)(ws + ((size_t)32 << 20));       //  8 MB  (reused for y)
    bf16_t* y_bf = x_bf;
    float* h = (float*)(ws + ((size_t)40 << 20));            // 16 MB
    bf16_t* wqkvT = (bf16_t*)(ws + ((size_t)56 << 20));      //  6 MB
    bf16_t* woT = (bf16_t*)(ws + ((size_t)62 << 20));        //  2 MB
    bf16_t* wfc0T = (bf16_t*)(ws + ((size_t)64 << 20));      //  8 MB
    bf16_t* wfc1T = (bf16_t*)(ws + ((size_t)72 << 20));      //  8 MB

    // weight transposes (fp32 -> bf16, K x N -> N x K)
    transpose_cast<<<dim3(3072 / 32, 1024 / 32), 256, 0, stream>>>(w_qkv, wqkvT, 1024, 3072);
    transpose_cast<<<dim3(1024 / 32, 1024 / 32), 256, 0, stream>>>(w_o, woT, 1024, 1024);
    transpose_cast<<<dim3(4096 / 32, 1024 / 32), 256, 0, stream>>>(w_fc0, wfc0T, 1024, 4096);
    transpose_cast<<<dim3(1024 / 32, 4096 / 32), 256, 0, stream>>>(w_fc1, wfc1T, 4096, 1024);

    // LN0 -> x_bf
    ln_kernel<<<L_, 256, 0, stream>>>(hidden, ln0_g, ln0_b, x_bf);

    // QKV gemm -> qkv bf16
    gemm_bt<0><<<dim3(3072 / 128, 4096 / 128), 256, 0, stream>>>(
        x_bf, wqkvT, L_, 3072, 1024, nullptr, qkv, nullptr, nullptr);

    // RoPE in place on q,k
    rope_kernel<<<(L_ * H_ * 32) / 256, 256, 0, stream>>>(qkv, freqs);

    // attention -> attn bf16
    attn_kernel<<<dim3(16, 16, 4), 256, 0, stream>>>(qkv, cu, attn);

    // W_O gemm + residual -> h fp32
    gemm_bt<1><<<dim3(1024 / 128, 4096 / 128), 256, 0, stream>>>(
        attn, woT, L_, 1024, 1024, h, nullptr, hidden, nullptr);

    // LN1 -> y_bf
    ln_kernel<<<L_, 256, 0, stream>>>(h, ln1_g, ln1_b, y_bf);

    // FC0 gemm + bias + gelu -> act bf16
    gemm_bt<2><<<dim3(4096 / 128, 4096 / 128), 256, 0, stream>>>(
        y_bf, wfc0T, L_, 4096, 1024, nullptr, act, b_fc0, nullptr);

    // FC1 gemm + bias + h -> out fp32
    gemm_bt<3><<<dim3(1024 / 128, 4096 / 128), 256, 0, stream>>>(
        act, wfc1T, L_, 1024, 4096, out, nullptr, b_fc1, h);
}

// Round 3
// 415.078 us; speedup vs baseline: 1.1201x; 1.1201x over previous
//
#include <hip/hip_runtime.h>
#include <cstdint>
#include <cmath>

#define L_ 4096
#define D_ 1024
#define H_ 16
#define HD_ 64
#define M_ 4096

typedef __bf16 bf16_t;
typedef __attribute__((ext_vector_type(8))) __bf16 bf16x8;
typedef __attribute__((ext_vector_type(4))) __bf16 bf16x4;
typedef __attribute__((ext_vector_type(4))) float f32x4;

__device__ __forceinline__ f32x4 mfma16(bf16x8 a, bf16x8 b, f32x4 c) {
    return __builtin_amdgcn_mfma_f32_16x16x32_bf16(a, b, c, 0, 0, 0);
}

__device__ __forceinline__ void gload_lds16(const bf16_t* g, bf16_t* l) {
    __builtin_amdgcn_global_load_lds(
        (const __attribute__((address_space(1))) unsigned int*)(g),
        (__attribute__((address_space(3))) unsigned int*)(l), 16, 0, 0);
}

// exp2 in one v_exp_f32 (library exp2f/expf carry range-reduction baggage)
__device__ __forceinline__ float fast_exp2(float x) {
    float r;
    asm volatile("v_exp_f32 %0, %1" : "=v"(r) : "v"(x));
    return r;
}

// ---------------------------------------------------------------------------
// LayerNorm: fp32 (rows x 1024) -> bf16 (float4 loads, bf16x4 stores)
// ---------------------------------------------------------------------------
__global__ __launch_bounds__(256) void ln_kernel(const float* __restrict__ x,
                                                 const float* __restrict__ g,
                                                 const float* __restrict__ b,
                                                 bf16_t* __restrict__ out) {
    int row = blockIdx.x, tid = threadIdx.x;
    int wave = tid >> 6, lane = tid & 63;
    const f32x4* xr = (const f32x4*)(x + (long)row * D_);
    f32x4 v = xr[tid];
    float s = v.x + v.y + v.z + v.w;
    __shared__ float red[8];
#pragma unroll
    for (int off = 32; off > 0; off >>= 1) s += __shfl_down(s, off, 64);
    if (lane == 0) red[wave] = s;
    __syncthreads();
    float mean = (red[0] + red[1] + red[2] + red[3]) * (1.f / 1024.f);
    float s2 = 0.f;
#pragma unroll
    for (int i = 0; i < 4; i++) { float d = v[i] - mean; s2 += d * d; }
#pragma unroll
    for (int off = 32; off > 0; off >>= 1) s2 += __shfl_down(s2, off, 64);
    __syncthreads();
    if (lane == 0) red[wave] = s2;
    __syncthreads();
    float var = (red[0] + red[1] + red[2] + red[3]) * (1.f / 1024.f);
    float rstd = rsqrtf(var + 1e-5f);
    f32x4 g4 = ((const f32x4*)g)[tid];
    f32x4 b4 = ((const f32x4*)b)[tid];
    bf16x4 o;
#pragma unroll
    for (int i = 0; i < 4; i++) o[i] = (bf16_t)((v[i] - mean) * rstd * g4[i] + b4[i]);
    *(bf16x4*)(out + (long)row * D_ + tid * 4) = o;
}

// ---------------------------------------------------------------------------
// All 4 weight transposes in one launch: W (K x N fp32) -> Wt (N x K bf16)
// tile ranges: [0,3072) qkv(1024x3072), [3072,4096) w_o(1024x1024),
//              [4096,8192) fc0(1024x4096), [8192,12288) fc1(4096x1024)
// ---------------------------------------------------------------------------
__global__ __launch_bounds__(256) void transpose_all(
    const float* __restrict__ w_qkv, const float* __restrict__ w_o,
    const float* __restrict__ w_fc0, const float* __restrict__ w_fc1,
    bf16_t* __restrict__ t_qkv, bf16_t* __restrict__ t_o,
    bf16_t* __restrict__ t_fc0, bf16_t* __restrict__ t_fc1) {
    __shared__ float t[32][33];
    int bidx = blockIdx.x;
    const float* W;
    bf16_t* Wt;
    int K, N, tile;
    if (bidx < 3072) { W = w_qkv; Wt = t_qkv; K = 1024; N = 3072; tile = bidx; }
    else if (bidx < 4096) { W = w_o; Wt = t_o; K = 1024; N = 1024; tile = bidx - 3072; }
    else if (bidx < 8192) { W = w_fc0; Wt = t_fc0; K = 1024; N = 4096; tile = bidx - 4096; }
    else { W = w_fc1; Wt = t_fc1; K = 4096; N = 1024; tile = bidx - 8192; }
    int nt = N >> 5;
    int n0 = (tile % nt) * 32, k0 = (tile / nt) * 32;
    int tx = threadIdx.x & 31, ty = threadIdx.x >> 5;
#pragma unroll
    for (int r = 0; r < 32; r += 8)
        t[ty + r][tx] = W[(long)(k0 + ty + r) * N + n0 + tx];
    __syncthreads();
#pragma unroll
    for (int r = 0; r < 32; r += 8)
        Wt[(long)(n0 + ty + r) * K + k0 + tx] = (bf16_t)t[tx][ty + r];
}

// ---------------------------------------------------------------------------
// V transpose: qkv v-part (L x 1024 @ col 2048) -> Vt[c][l]  (1024 x 4096 bf16)
// ---------------------------------------------------------------------------
__global__ __launch_bounds__(256) void vt_kernel(const bf16_t* __restrict__ qkv,
                                                 bf16_t* __restrict__ Vt) {
    __shared__ bf16_t t[32][33];
    int l0 = blockIdx.x * 32, c0 = blockIdx.y * 32;
    int tx = threadIdx.x & 31, ty = threadIdx.x >> 5;
#pragma unroll
    for (int r = 0; r < 32; r += 8)
        t[ty + r][tx] = qkv[(long)(l0 + ty + r) * 3072 + 2048 + c0 + tx];
    __syncthreads();
#pragma unroll
    for (int r = 0; r < 32; r += 8)
        Vt[(long)(c0 + ty + r) * 4096 + l0 + tx] = t[tx][ty + r];
}

// ---------------------------------------------------------------------------
// RoPE on q,k: vectorized 16B loads/stores. thread = (l, h, g), g = 4 d2-pairs
// ---------------------------------------------------------------------------
__global__ __launch_bounds__(256) void rope_kernel(bf16_t* __restrict__ qkv,
                                                   const float* __restrict__ freqs) {
    int idx = blockIdx.x * 256 + threadIdx.x;  // L*H*8
    int g = idx & 7;
    int h = (idx >> 3) & 15;
    int l = idx >> 7;
    const float* f = freqs + (long)l * 64 + g * 8;  // 4 pairs (c,s)
    f32x4 f0 = ((const f32x4*)f)[0];
    f32x4 f1 = ((const f32x4*)f)[1];
    float c[4] = {f0.x, f0.z, f1.x, f1.z};
    float s[4] = {f0.y, f0.w, f1.y, f1.w};
    bf16_t* qp = qkv + (long)l * 3072 + h * 64 + g * 8;
    bf16x8 q = *(bf16x8*)qp;
    bf16x8 k = *(bf16x8*)(qp + 1024);
    bf16x8 qo, ko;
#pragma unroll
    for (int e = 0; e < 4; e++) {
        float a = (float)q[2 * e], b = (float)q[2 * e + 1];
        qo[2 * e] = (bf16_t)(a * c[e] - b * s[e]);
        qo[2 * e + 1] = (bf16_t)(a * s[e] + b * c[e]);
        a = (float)k[2 * e]; b = (float)k[2 * e + 1];
        ko[2 * e] = (bf16_t)(a * c[e] - b * s[e]);
        ko[2 * e + 1] = (bf16_t)(a * s[e] + b * c[e]);
    }
    *(bf16x8*)qp = qo;
    *(bf16x8*)(qp + 1024) = ko;
}

// ---------------------------------------------------------------------------
// GEMM 128x128x32 (m97 structure), epilogues as before
// ---------------------------------------------------------------------------
template <int EPI>
__global__ __launch_bounds__(256) void gemm_bt(const bf16_t* __restrict__ A,
                                               const bf16_t* __restrict__ Bt,
                                               int M, int N, int K,
                                               float* __restrict__ outF,
                                               bf16_t* __restrict__ outB,
                                               const float* __restrict__ extra1,
                                               const float* __restrict__ extra2) {
    __shared__ __align__(16) bf16_t As[128 * 32];
    __shared__ __align__(16) bf16_t Bs[128 * 32];
    int tid = threadIdx.x;
    int wave = tid >> 6, lane = tid & 63;
    int quad = lane >> 4, l16 = lane & 15;
    int wr = wave >> 1, wc = wave & 1;
    long bm = (long)blockIdx.y * 128, bn = (long)blockIdx.x * 128;

    f32x4 acc[4][4];
#pragma unroll
    for (int i = 0; i < 4; i++)
#pragma unroll
        for (int j = 0; j < 4; j++) acc[i][j] = (f32x4){0.f, 0.f, 0.f, 0.f};

    const bf16_t* a_base = A + (bm + wave * 32 + (lane >> 2)) * (long)K + (lane & 3) * 8;
    const bf16_t* b_base = Bt + (bn + wave * 32 + (lane >> 2)) * (long)K + (lane & 3) * 8;
    bf16_t* as_dst0 = &As[(wave * 32 + 0) * 32];
    bf16_t* as_dst1 = &As[(wave * 32 + 16) * 32];
    bf16_t* bs_dst0 = &Bs[(wave * 32 + 0) * 32];
    bf16_t* bs_dst1 = &Bs[(wave * 32 + 16) * 32];

    for (int k0 = 0; k0 < K; k0 += 32) {
        __syncthreads();
        gload_lds16(a_base + k0, as_dst0);
        gload_lds16(a_base + k0 + (long)16 * K, as_dst1);
        gload_lds16(b_base + k0, bs_dst0);
        gload_lds16(b_base + k0 + (long)16 * K, bs_dst1);
        __builtin_amdgcn_s_waitcnt(0);
        __syncthreads();

        bf16x8 af[4], bf[4];
#pragma unroll
        for (int i = 0; i < 4; i++) {
            af[i] = *(const bf16x8*)&As[(wr * 64 + i * 16 + l16) * 32 + quad * 8];
            bf[i] = *(const bf16x8*)&Bs[(wc * 64 + i * 16 + l16) * 32 + quad * 8];
        }
#pragma unroll
        for (int i = 0; i < 4; i++)
#pragma unroll
            for (int j = 0; j < 4; j++)
                acc[i][j] = mfma16(af[i], bf[j], acc[i][j]);
    }

    long base_row = bm + wr * 64;
    long base_col = bn + wc * 64;
#pragma unroll
    for (int i = 0; i < 4; i++)
#pragma unroll
        for (int j = 0; j < 4; j++)
#pragma unroll
            for (int r = 0; r < 4; r++) {
                long row = base_row + i * 16 + quad * 4 + r;
                long col = base_col + j * 16 + l16;
                long idx = row * (long)N + col;
                float v = acc[i][j][r];
                if (EPI == 0) {
                    outB[idx] = (bf16_t)v;
                } else if (EPI == 1) {
                    outF[idx] = v + extra1[idx];
                } else if (EPI == 2) {
                    v += extra1[col];
                    v = 0.5f * v * (1.0f + erff(v * 0.70710678118f));
                    outB[idx] = (bf16_t)v;
                } else {
                    outF[idx] = v + extra1[col] + extra2[idx];
                }
            }
}

// ---------------------------------------------------------------------------
// GEMM 128x64x32 for N=1024 outputs (W_O, FC1): grid 512 = 2 blocks/CU
// ---------------------------------------------------------------------------
template <int EPI>
__global__ __launch_bounds__(256) void gemm_bt64(const bf16_t* __restrict__ A,
                                                 const bf16_t* __restrict__ Bt,
                                                 int M, int N, int K,
                                                 float* __restrict__ outF,
                                                 const float* __restrict__ extra1,
                                                 const float* __restrict__ extra2) {
    __shared__ __align__(16) bf16_t As[128 * 32];
    __shared__ __align__(16) bf16_t Bs[64 * 32];
    int tid = threadIdx.x;
    int wave = tid >> 6, lane = tid & 63;
    int quad = lane >> 4, l16 = lane & 15;
    long bm = (long)blockIdx.y * 128, bn = (long)blockIdx.x * 64;

    f32x4 acc[2][4];
#pragma unroll
    for (int i = 0; i < 2; i++)
#pragma unroll
        for (int j = 0; j < 4; j++) acc[i][j] = (f32x4){0.f, 0.f, 0.f, 0.f};

    const bf16_t* a_base = A + (bm + wave * 32 + (lane >> 2)) * (long)K + (lane & 3) * 8;
    const bf16_t* b_base = Bt + (bn + wave * 16 + (lane >> 2)) * (long)K + (lane & 3) * 8;
    bf16_t* as_dst0 = &As[(wave * 32 + 0) * 32];
    bf16_t* as_dst1 = &As[(wave * 32 + 16) * 32];
    bf16_t* bs_dst = &Bs[(wave * 16) * 32];

    for (int k0 = 0; k0 < K; k0 += 32) {
        __syncthreads();
        gload_lds16(a_base + k0, as_dst0);
        gload_lds16(a_base + k0 + (long)16 * K, as_dst1);
        gload_lds16(b_base + k0, bs_dst);
        __builtin_amdgcn_s_waitcnt(0);
        __syncthreads();

        bf16x8 af[2], bf[4];
#pragma unroll
        for (int i = 0; i < 2; i++)
            af[i] = *(const bf16x8*)&As[(wave * 32 + i * 16 + l16) * 32 + quad * 8];
#pragma unroll
        for (int j = 0; j < 4; j++)
            bf[j] = *(const bf16x8*)&Bs[(j * 16 + l16) * 32 + quad * 8];
#pragma unroll
        for (int i = 0; i < 2; i++)
#pragma unroll
            for (int j = 0; j < 4; j++)
                acc[i][j] = mfma16(af[i], bf[j], acc[i][j]);
    }

#pragma unroll
    for (int i = 0; i < 2; i++)
#pragma unroll
        for (int j = 0; j < 4; j++)
#pragma unroll
            for (int r = 0; r < 4; r++) {
                long row = bm + wave * 32 + i * 16 + quad * 4 + r;
                long col = bn + j * 16 + l16;
                long idx = row * (long)N + col;
                float v = acc[i][j][r];
                if (EPI == 1) {
                    outF[idx] = v + extra1[idx];
                } else {
                    outF[idx] = v + extra1[col] + extra2[idx];
                }
            }
}

// ---------------------------------------------------------------------------
// Flash attention, swizzled LDS staging, exp2-domain softmax.
// grid (qt=16, head=16, seg=4), 256 threads.
// ---------------------------------------------------------------------------
__global__ __launch_bounds__(256) void attn_kernel(const bf16_t* __restrict__ qkv,
                                                   const bf16_t* __restrict__ Vt,
                                                   const int* __restrict__ cu,
                                                   bf16_t* __restrict__ out) {
    __shared__ __align__(16) bf16_t Qs[64 * 64];
    __shared__ __align__(16) bf16_t Ks[64 * 64];
    __shared__ __align__(16) bf16_t Vs[64 * 64];     // Vs[hd][key], chunk-swizzled
    __shared__ __align__(16) bf16_t Ps[4][16 * 72];  // stride 72: 144B rows, 16B-aligned

    int tid = threadIdx.x, wave = tid >> 6, lane = tid & 63;
    int quad = lane >> 4, l16 = lane & 15;
    int qt = blockIdx.x, head = blockIdx.y, seg = blockIdx.z;
    int s0 = cu[seg], s1 = cu[seg + 1];
    int r0 = s0 + qt * 64;
    const long hoff = (long)head * 64;

    // staging geometry (same for Q/K/V): lane -> row lr, swizzled chunk sc
    int lr = lane >> 3;                     // row within 8-row group
    int sc = (lane & 7) ^ (lr & 7);         // XOR chunk swizzle
    // swizzled read slot for A/B frags, per (ks,quad): slot = (ks*4+quad)^(l16&7)
    int sl0 = (0 * 4 + quad) ^ (l16 & 7);
    int sl1 = (1 * 4 + quad) ^ (l16 & 7);

    // stage Q once
#pragma unroll
    for (int i = 0; i < 2; i++) {
        int row = wave * 16 + i * 8 + lr;
        gload_lds16(qkv + (long)(r0 + row) * 3072 + hoff + sc * 8,
                    &Qs[(wave * 16 + i * 8) * 64]);
    }

    f32x4 o[4];
#pragma unroll
    for (int j = 0; j < 4; j++) o[j] = (f32x4){0.f, 0.f, 0.f, 0.f};
    float mrow[4], lrow[4];
#pragma unroll
    for (int r = 0; r < 4; r++) { mrow[r] = -1e30f; lrow[r] = 0.f; }

    const float k1 = 0.125f * 1.44269504089f;  // scale * log2(e)

    for (int kt = s0; kt < s1; kt += 64) {
        __syncthreads();
#pragma unroll
        for (int i = 0; i < 2; i++) {
            int row = wave * 16 + i * 8 + lr;
            gload_lds16(qkv + (long)(kt + row) * 3072 + 1024 + hoff + sc * 8,
                        &Ks[(wave * 16 + i * 8) * 64]);
            gload_lds16(Vt + (hoff + row) * (long)4096 + kt + sc * 8,
                        &Vs[(wave * 16 + i * 8) * 64]);
        }
        __builtin_amdgcn_s_waitcnt(0);
        __syncthreads();

        // S strip (16 q-rows x 64 keys)
        f32x4 sacc[4];
#pragma unroll
        for (int j = 0; j < 4; j++) sacc[j] = (f32x4){0.f, 0.f, 0.f, 0.f};
        bf16x8 aq0 = *(const bf16x8*)&Qs[(wave * 16 + l16) * 64 + sl0 * 8];
        bf16x8 aq1 = *(const bf16x8*)&Qs[(wave * 16 + l16) * 64 + sl1 * 8];
#pragma unroll
        for (int j = 0; j < 4; j++) {
            bf16x8 b0 = *(const bf16x8*)&Ks[(j * 16 + l16) * 64 + sl0 * 8];
            bf16x8 b1 = *(const bf16x8*)&Ks[(j * 16 + l16) * 64 + sl1 * 8];
            sacc[j] = mfma16(aq0, b0, sacc[j]);
            sacc[j] = mfma16(aq1, b1, sacc[j]);
        }

        // online softmax in log2 domain
        float alpha[4];
#pragma unroll
        for (int r = 0; r < 4; r++) {
            float mx = fmaxf(fmaxf(sacc[0][r], sacc[1][r]), fmaxf(sacc[2][r], sacc[3][r]));
#pragma unroll
            for (int off = 1; off < 16; off <<= 1) mx = fmaxf(mx, __shfl_xor(mx, off, 64));
            mx *= k1;
            float mnew = fmaxf(mrow[r], mx);
            alpha[r] = fast_exp2(mrow[r] - mnew);
            mrow[r] = mnew;
        }
        float rs[4] = {0.f, 0.f, 0.f, 0.f};
#pragma unroll
        for (int j = 0; j < 4; j++)
#pragma unroll
            for (int r = 0; r < 4; r++) {
                float p = fast_exp2(sacc[j][r] * k1 - mrow[r]);
                rs[r] += p;
                Ps[wave][(quad * 4 + r) * 72 + j * 16 + l16] = (bf16_t)p;
            }
#pragma unroll
        for (int r = 0; r < 4; r++) {
#pragma unroll
            for (int off = 1; off < 16; off <<= 1) rs[r] += __shfl_xor(rs[r], off, 64);
            lrow[r] = lrow[r] * alpha[r] + rs[r];
        }
#pragma unroll
        for (int j = 0; j < 4; j++)
#pragma unroll
            for (int r = 0; r < 4; r++) o[j][r] *= alpha[r];

        __builtin_amdgcn_s_waitcnt(0);  // Ps ds_write -> ds_read (same wave)

        // O += P @ V
        bf16x8 ap0 = *(const bf16x8*)&Ps[wave][l16 * 72 + 0 * 32 + quad * 8];
        bf16x8 ap1 = *(const bf16x8*)&Ps[wave][l16 * 72 + 1 * 32 + quad * 8];
#pragma unroll
        for (int j2 = 0; j2 < 4; j2++) {
            bf16x8 b0 = *(const bf16x8*)&Vs[(j2 * 16 + l16) * 64 + sl0 * 8];
            bf16x8 b1 = *(const bf16x8*)&Vs[(j2 * 16 + l16) * 64 + sl1 * 8];
            o[j2] = mfma16(ap0, b0, o[j2]);
            o[j2] = mfma16(ap1, b1, o[j2]);
        }
    }

#pragma unroll
    for (int j2 = 0; j2 < 4; j2++)
#pragma unroll
        for (int r = 0; r < 4; r++) {
            int row = r0 + wave * 16 + quad * 4 + r;
            out[(long)row * 1024 + head * 64 + j2 * 16 + l16] = (bf16_t)(o[j2][r] / lrow[r]);
        }
}

// ---------------------------------------------------------------------------
extern "C" void kernel_launch(void* const* d_in, const int* in_sizes, int n_in,
                              void* d_out, int out_size, void* d_ws, size_t ws_size,
                              hipStream_t stream) {
    const float* hidden = (const float*)d_in[0];
    const int* cu = (const int*)d_in[1];
    const float* freqs = (const float*)d_in[2];
    const float* ln0_g = (const float*)d_in[3];
    const float* ln0_b = (const float*)d_in[4];
    const float* ln1_g = (const float*)d_in[5];
    const float* ln1_b = (const float*)d_in[6];
    const float* w_qkv = (const float*)d_in[7];
    const float* w_o = (const float*)d_in[8];
    const float* w_fc0 = (const float*)d_in[9];
    const float* b_fc0 = (const float*)d_in[10];
    const float* w_fc1 = (const float*)d_in[11];
    const float* b_fc1 = (const float*)d_in[12];
    float* out = (float*)d_out;

    char* ws = (char*)d_ws;
    bf16_t* qkv = (bf16_t*)(ws);                             // 24 MB [0,24)
    bf16_t* attn = (bf16_t*)(ws + ((size_t)24 << 20));       //  8 MB [24,32)
    bf16_t* act = (bf16_t*)(ws);                             // 32 MB [0,32) after attn dead
    bf16_t* x_bf = (bf16_t*)(ws + ((size_t)32 << 20));       //  8 MB [32,40)
    bf16_t* Vt = x_bf;                                       //  8 MB (x_bf dead after QKV gemm)
    bf16_t* y_bf = x_bf;                                     //  (Vt dead after attn)
    float* h = (float*)(ws + ((size_t)40 << 20));            // 16 MB [40,56)
    bf16_t* wqkvT = (bf16_t*)(ws + ((size_t)56 << 20));      //  6 MB
    bf16_t* woT = (bf16_t*)(ws + ((size_t)62 << 20));        //  2 MB
    bf16_t* wfc0T = (bf16_t*)(ws + ((size_t)64 << 20));      //  8 MB
    bf16_t* wfc1T = (bf16_t*)(ws + ((size_t)72 << 20));      //  8 MB

    transpose_all<<<12288, 256, 0, stream>>>(w_qkv, w_o, w_fc0, w_fc1,
                                             wqkvT, woT, wfc0T, wfc1T);

    ln_kernel<<<L_, 256, 0, stream>>>(hidden, ln0_g, ln0_b, x_bf);

    gemm_bt<0><<<dim3(3072 / 128, 4096 / 128), 256, 0, stream>>>(
        x_bf, wqkvT, L_, 3072, 1024, nullptr, qkv, nullptr, nullptr);

    rope_kernel<<<(L_ * H_ * 8) / 256, 256, 0, stream>>>(qkv, freqs);
    vt_kernel<<<dim3(4096 / 32, 1024 / 32), 256, 0, stream>>>(qkv, Vt);

    attn_kernel<<<dim3(16, 16, 4), 256, 0, stream>>>(qkv, Vt, cu, attn);

    gemm_bt64<1><<<dim3(1024 / 64, 4096 / 128), 256, 0, stream>>>(
        attn, woT, L_, 1024, 1024, h, hidden, nullptr);

    ln_kernel<<<L_, 256, 0, stream>>>(h, ln1_g, ln1_b, y_bf);

    gemm_bt<2><<<dim3(4096 / 128, 4096 / 128), 256, 0, stream>>>(
        y_bf, wfc0T, L_, 4096, 1024, nullptr, act, b_fc0, nullptr);

    gemm_bt64<3><<<dim3(1024 / 64, 4096 / 128), 256, 0, stream>>>(
        act, wfc1T, L_, 1024, 4096, out, b_fc1, h);
}